// Round 18
// baseline (753.116 us; speedup 1.0000x reference)
//
#include <hip/hip_runtime.h>
#include <math.h>

#define KCODES 4096
#define DIM    256
#define HW     4096
#define NPIX   65536
#define NQ     16777216   // 16*256*64*64
#define EPSW   3.0e-4f    // hh-only scan: eps_max ~1.25e-4 rigorous; EPSW >= 2*eps

typedef _Float16 f16x8 __attribute__((ext_vector_type(8)));
typedef float    f32x4 __attribute__((ext_vector_type(4)));

// XOR swizzle on tile-local byte offset (within 8KB chunk of 128 rows x 64B).
#define SWZ(x) ((x) ^ ((((x) >> 6) & 7) << 4))

static __device__ __forceinline__ void gld16(const void* g, void* l) {
    __builtin_amdgcn_global_load_lds(
        (const __attribute__((address_space(1))) void*)g,
        (__attribute__((address_space(3))) void*)l, 16, 0, 0);
}

// top4 insert, strict < (ascending-k feed => lowest k kept on ties; a tie-drop
// at V[3] is covered by the m3<=lim rescan flag)
#define INS4(V, I, dd, kk) do { \
  if ((dd) < V[3]) { \
    if ((dd) < V[1]) { \
      V[3]=V[2]; I[3]=I[2]; V[2]=V[1]; I[2]=I[1]; \
      if ((dd) < V[0]) { V[1]=V[0]; I[1]=I[0]; V[0]=(dd); I[0]=(kk); } \
      else             { V[1]=(dd); I[1]=(kk); } \
    } else { \
      if ((dd) < V[2]) { V[3]=V[2]; I[3]=I[2]; V[2]=(dd); I[2]=(kk); } \
      else             { V[3]=(dd); I[3]=(kk); } \
    } } } while(0)

// top8 insert (merge-time only), strict <; tie-drops at V[7] covered by flag
#define INS8(V, I, dd, kk) do { \
  if ((dd) < V[7]) { \
    if ((dd) < V[3]) { \
      V[7]=V[6];I[7]=I[6];V[6]=V[5];I[6]=I[5];V[5]=V[4];I[5]=I[4];V[4]=V[3];I[4]=I[3]; \
      if ((dd) < V[1]) { \
        V[3]=V[2];I[3]=I[2];V[2]=V[1];I[2]=I[1]; \
        if ((dd) < V[0]) { V[1]=V[0];I[1]=I[0];V[0]=(dd);I[0]=(kk); } \
        else             { V[1]=(dd);I[1]=(kk); } \
      } else { \
        if ((dd) < V[2]) { V[3]=V[2];I[3]=I[2];V[2]=(dd);I[2]=(kk); } \
        else             { V[3]=(dd);I[3]=(kk); } \
      } \
    } else { \
      if ((dd) < V[5]) { \
        V[7]=V[6];I[7]=I[6];V[6]=V[5];I[6]=I[5]; \
        if ((dd) < V[4]) { V[5]=V[4];I[5]=I[4];V[4]=(dd);I[4]=(kk); } \
        else             { V[5]=(dd);I[5]=(kk); } \
      } else { \
        if ((dd) < V[6]) { V[7]=V[6];I[7]=I[6];V[6]=(dd);I[6]=(kk); } \
        else             { V[7]=(dd);I[7]=(kk); } \
      } \
    } } } while(0)

// ---------------------------------------------------------------------------
// np-exact helpers (bit-replicate numpy f32 semantics — proven in R3)
// ---------------------------------------------------------------------------
__global__ __launch_bounds__(256) void ee_np_kernel(const float* __restrict__ emb,
                                                    float* __restrict__ ee) {
#pragma clang fp contract(off)
    const int k = blockIdx.x * 256 + threadIdx.x;
    const float* a = emb + (size_t)k * DIM;
    float res[2];
    #pragma unroll
    for (int h = 0; h < 2; ++h) {
        const float* b = a + h * 128;
        float r[8];
        #pragma unroll
        for (int j = 0; j < 8; ++j) { const float x = b[j]; r[j] = x * x; }
        for (int i = 8; i < 128; i += 8) {
            #pragma unroll
            for (int j = 0; j < 8; ++j) { const float x = b[i + j]; r[j] += x * x; }
        }
        res[h] = ((r[0] + r[1]) + (r[2] + r[3])) + ((r[4] + r[5]) + (r[6] + r[7]));
    }
    ee[k] = res[0] + res[1];
}

__global__ __launch_bounds__(256) void zz_np_kernel(const float* __restrict__ z,
                                                    float* __restrict__ zz) {
#pragma clang fp contract(off)
    const int n  = blockIdx.x * 256 + threadIdx.x;
    const int b  = n >> 12;
    const int hw = n & (HW - 1);
    const float* base = z + (size_t)b * DIM * HW + hw;
    float res[2];
    #pragma unroll
    for (int h = 0; h < 2; ++h) {
        const float* p = base + (size_t)(h * 128) * HW;
        float r[8];
        #pragma unroll
        for (int j = 0; j < 8; ++j) { const float x = p[(size_t)j * HW]; r[j] = x * x; }
        for (int i = 8; i < 128; i += 8) {
            #pragma unroll
            for (int j = 0; j < 8; ++j) { const float x = p[(size_t)(i + j) * HW]; r[j] += x * x; }
        }
        res[h] = ((r[0] + r[1]) + (r[2] + r[3])) + ((r[4] + r[5]) + (r[6] + r[7]));
    }
    zz[n] = res[0] + res[1];
}

__device__ float np_dist(const float* __restrict__ z, const float* __restrict__ emb,
                         const float* __restrict__ zz, const float* __restrict__ ee,
                         int n, int k) {
    const int b = n >> 12, hw = n & (HW - 1);
    const float* zp = z + (size_t)b * DIM * HW + hw;
    const float* ep = emb + (size_t)k * DIM;
    float m = 0.0f;
    for (int i = 0; i < DIM; ++i) m = fmaf(zp[(size_t)i * HW], ep[i], m);
    const float t = zz[n] + ee[k];
    return t - 2.0f * m;
}

// ---------------------------------------------------------------------------
// FAST path kernels
// ---------------------------------------------------------------------------
// emb -> tiled fp16 HI only, scaled by 4096 (exact pow2), PRE-SWIZZLED.
__global__ __launch_bounds__(256) void cvt_emb_kernel(const float* __restrict__ emb,
                                                      ushort* __restrict__ eh) {
    const int t = threadIdx.x;
    const int k = blockIdx.x * 4 + (t >> 6);
    const int seg = t & 63;                       // 4-elem segment
    const float4 v = *reinterpret_cast<const float4*>(emb + (size_t)k * DIM + seg * 4);
    union H4 { _Float16 h[4]; short4 s; } uh;
    const float vv[4] = {v.x, v.y, v.z, v.w};
    #pragma unroll
    for (int j = 0; j < 4; ++j) uh.h[j] = (_Float16)(vv[j] * 4096.0f);
    const int s = seg >> 3;
    const int y  = (k & 127) * 64 + (seg & 7) * 8;        // logical byte in 8KB chunk
    const int ys = y ^ ((k & 7) << 4);                    // pre-swizzled
    const size_t addr = (size_t)(k >> 7) * 32768 + s * 4096 + (ys >> 1);
    *reinterpret_cast<short4*>(eh + addr) = uh.s;
}

// z (NCHW) -> transposed tiled fp16 HI [pixel][dim], PRE-SWIZZLED.
__global__ __launch_bounds__(256) void cvt_z_kernel(const float* __restrict__ z,
                                                    ushort* __restrict__ zh) {
    __shared__ float ls[64][65];
    const int t = threadIdx.x;
    const int bid = blockIdx.x;
    const int b = bid >> 8, cc = (bid >> 6) & 3, hh = bid & 63;
    const int col = t & 63, r0 = t >> 6;
    #pragma unroll
    for (int i = 0; i < 16; ++i) {
        const int r = i * 4 + r0;
        ls[r][col] = z[((size_t)(b * DIM + cc * 64 + r)) * HW + hh * 64 + col];
    }
    __syncthreads();
    const int pxl = t >> 2, cseg = t & 3;
    const int px = b * HW + hh * 64 + pxl;
    const int sg = cc * 2 + (cseg >> 1);
    union H8 { _Float16 h[8]; int4 v; } ha, hb;
    #pragma unroll
    for (int j = 0; j < 16; ++j) {
        const float val = ls[cseg * 16 + j][pxl];
        if (j < 8) ha.h[j] = (_Float16)val;
        else       hb.h[j - 8] = (_Float16)val;
    }
    const size_t chunk = (size_t)(px >> 7) * 32768 + sg * 4096;
    const int y1  = (px & 127) * 64 + (cseg & 1) * 32;
    const int msk = (px & 7) << 4;
    *reinterpret_cast<int4*>(zh + chunk + ((y1 ^ msk) >> 1))        = ha.v;
    *reinterpret_cast<int4*>(zh + chunk + (((y1 + 16) ^ msk) >> 1)) = hb.v;
}

// MFMA distance pass (hh-only): block = 64 pixels x 4096 codes.
// z fragments register-resident; code chunks TRIPLE-buffered with distance-2
// prefetch and COUNTED vmcnt(4) (never 0 in-loop) + raw s_barrier; ee staged
// in LDS so in-loop VMEM count is exactly 4 gld16/phase. R16 epilogue.
__global__ __launch_bounds__(256, 2) void gemm_kernel(const ushort* __restrict__ eh,
                                                      const ushort* __restrict__ zh,
                                                      const float* __restrict__ ee,
                                                      const float* __restrict__ zz,
                                                      float* __restrict__ top8v,
                                                      int* __restrict__ top8i,
                                                      float* __restrict__ m3f) {
    __shared__ __align__(16) char lds[65536];    // buf0@0 buf1@16K buf2@32K ee@48K

    const int t = threadIdx.x;
    const int lane = t & 63, w = t >> 6, wr = w >> 1, wc = w & 1;
    const int l15 = lane & 15, l4 = lane >> 4;
    const int bid = blockIdx.x;
    const int px0 = bid * 64;
    const int lo = t * 16;            // per-lane linear byte offset within 4KB round
    const int wb = w * 1024;          // wave-uniform LDS base
    const char* ehB = (const char*)eh;
    char* const eel = lds + 49152;

    // ---- load z fragments into registers (once) ----
    f16x8 zr[2][8];
    {
        const size_t chunk = (size_t)(bid >> 1) * 32768;   // halfs
        #pragma unroll
        for (int ni = 0; ni < 2; ++ni) {
            const int lr = (bid & 1) * 64 + wc * 32 + ni * 16 + l15;  // row in 128-chunk
            const int ro = SWZ(lr * 64 + l4 * 16) >> 1;               // halfs
            #pragma unroll
            for (int s = 0; s < 8; ++s)
                zr[ni][s] = *reinterpret_cast<const f16x8*>(zh + chunk + s * 4096 + ro);
        }
    }
    float zzr[2];
    #pragma unroll
    for (int ni = 0; ni < 2; ++ni) zzr[ni] = zz[px0 + wc * 32 + ni * 16 + l15];

    // per-lane code-fragment byte offsets within an 8KB dim-subchunk
    int aoff[4];
    #pragma unroll
    for (int mi = 0; mi < 4; ++mi)
        aoff[mi] = SWZ((wr * 64 + mi * 16 + l15) * 64 + l4 * 16);

    // ---- prologue staging: ee (16KB), chunk0 -> buf0, chunk1 -> buf1 ----
    #pragma unroll
    for (int r = 0; r < 4; ++r)
        gld16((const char*)ee + r * 4096 + lo, eel + r * 4096 + wb);
    #pragma unroll
    for (int r = 0; r < 4; ++r)
        gld16(ehB + r * 4096 + lo, lds + r * 4096 + wb);
    #pragma unroll
    for (int r = 0; r < 4; ++r)
        gld16(ehB + 16384 + r * 4096 + lo, lds + 16384 + r * 4096 + wb);

    float Tv[2][4]; int Ti[2][4];
    #pragma unroll
    for (int ni = 0; ni < 2; ++ni)
        #pragma unroll
        for (int j = 0; j < 4; ++j) { Tv[ni][j] = 3.0e38f; Ti[ni][j] = 0; }

    f32x4 acc[4][2];
    char* B0 = lds;                 // read buffer for current phase
    char* B1 = lds + 16384;         // next
    char* B2 = lds + 32768;         // write target (phase+2)

    for (int ph = 0; ph < 128; ++ph) {
        const int p = ph >> 2, st = ph & 3;
        // counted wait: batch for B0 (issued 2 phases ago) is done when <=4 remain
        asm volatile("s_waitcnt vmcnt(4)" ::: "memory");
        __builtin_amdgcn_sched_barrier(0);
        __builtin_amdgcn_s_barrier();   // all waves: B0 visible; B2 readers done
        // issue prefetch for phase ph+2 into B2 (wrap keeps count uniform; safe)
        {
            const size_t src = (size_t)((ph + 2) & 127) * 16384;
            #pragma unroll
            for (int r = 0; r < 4; ++r)
                gld16(ehB + src + r * 4096 + lo, B2 + r * 4096 + wb);
        }
        if (st == 0) {
            #pragma unroll
            for (int mi = 0; mi < 4; ++mi)
                #pragma unroll
                for (int ni = 0; ni < 2; ++ni)
                    acc[mi][ni] = (f32x4){0.0f, 0.0f, 0.0f, 0.0f};
        }
        #pragma unroll
        for (int sp = 0; sp < 2; ++sp) {
            const int sg = st * 2 + sp;    // global s 0..7
            f16x8 aH[4];
            #pragma unroll
            for (int mi = 0; mi < 4; ++mi)
                aH[mi] = *reinterpret_cast<const f16x8*>(B0 + sp * 8192 + aoff[mi]);
            #pragma unroll
            for (int mi = 0; mi < 4; ++mi)
                #pragma unroll
                for (int ni = 0; ni < 2; ++ni)
                    acc[mi][ni] = __builtin_amdgcn_mfma_f32_16x16x32_f16(aH[mi], zr[ni][sg], acc[mi][ni], 0, 0, 0);
        }
        if (st == 3) {
            // epilogue (R16-proven): d = fl((zz+ee) - acc*2^-11), per-thread top4
            float eer[4][4];
            #pragma unroll
            for (int mi = 0; mi < 4; ++mi)
                *reinterpret_cast<float4*>(&eer[mi][0]) =
                    *reinterpret_cast<const float4*>(eel + (size_t)(p * 128 + wr * 64 + mi * 16 + l4 * 4) * 4);
            #pragma unroll
            for (int ni = 0; ni < 2; ++ni) {
                const float zzc = zzr[ni];
                #pragma unroll
                for (int mi = 0; mi < 4; ++mi) {
                    #pragma unroll
                    for (int r = 0; r < 4; ++r) {
                        const float tt = zzc + eer[mi][r];
                        const float d = fmaf(acc[mi][ni][r], -4.8828125e-4f, tt);
                        const int k = p * 128 + wr * 64 + mi * 16 + l4 * 4 + r;
                        INS4(Tv[ni], Ti[ni], d, k);
                    }
                }
            }
        }
        // rotate buffers
        char* tmp = B0; B0 = B1; B1 = B2; B2 = tmp;
    }

    asm volatile("s_waitcnt vmcnt(0)" ::: "memory");  // drain wrapped prefetches
    __syncthreads();                                  // before aliasing LDS

    // merge arrays alias the code buffer region (fully drained)
    float (*mv)[64][8]  = reinterpret_cast<float (*)[64][8]>(&lds[0]);
    int   (*mi_)[64][8] = reinterpret_cast<int (*)[64][8]>(&lds[8192]);
    float (*m3s)[64]    = reinterpret_cast<float (*)[64]>(&lds[16384]);

    // per-ni: expand top4 -> top8, merge across l4 lanes (xor16/xor32), track m3
    #pragma unroll
    for (int ni = 0; ni < 2; ++ni) {
        float fv[8]; int fi[8];
        #pragma unroll
        for (int j = 0; j < 4; ++j) { fv[j] = Tv[ni][j]; fi[j] = Ti[ni][j]; }
        #pragma unroll
        for (int j = 4; j < 8; ++j) { fv[j] = 3.0e38f; fi[j] = 0; }
        float m3 = Tv[ni][3];          // pre-merge thread-local 4th best
        #pragma unroll
        for (int m = 16; m <= 32; m <<= 1) {
            float ov[8]; int oi[8];
            #pragma unroll
            for (int j = 0; j < 8; ++j) {
                ov[j] = __shfl_xor(fv[j], m, 64);
                oi[j] = __shfl_xor(fi[j], m, 64);
            }
            const float om = __shfl_xor(m3, m, 64);
            #pragma unroll
            for (int j = 0; j < 8; ++j) INS8(fv, fi, ov[j], oi[j]);
            m3 = fminf(m3, om);
        }
        if (lane < 16) {
            const int c = wc * 32 + ni * 16 + lane;
            #pragma unroll
            for (int j = 0; j < 8; ++j) { mv[wr][c][j] = fv[j]; mi_[wr][c][j] = fi[j]; }
            m3s[wr][c] = m3;
        }
    }
    __syncthreads();
    if (t < 64) {
        float fv[8]; int fi[8];
        #pragma unroll
        for (int j = 0; j < 8; ++j) { fv[j] = mv[0][t][j]; fi[j] = mi_[0][t][j]; }
        #pragma unroll
        for (int j = 0; j < 8; ++j) INS8(fv, fi, mv[1][t][j], mi_[1][t][j]);
        const float m3 = fminf(m3s[0][t], m3s[1][t]);
        const int px = px0 + t;
        *reinterpret_cast<float4*>(top8v + (size_t)px * 8)     = make_float4(fv[0], fv[1], fv[2], fv[3]);
        *reinterpret_cast<float4*>(top8v + (size_t)px * 8 + 4) = make_float4(fv[4], fv[5], fv[6], fv[7]);
        *reinterpret_cast<int4*>(top8i + (size_t)px * 8)       = make_int4(fi[0], fi[1], fi[2], fi[3]);
        *reinterpret_cast<int4*>(top8i + (size_t)px * 8 + 4)   = make_int4(fi[4], fi[5], fi[6], fi[7]);
        m3f[px] = m3;
    }
}

// resolve: shortcut / np-exact candidate re-evaluation / rescan flagging
__global__ __launch_bounds__(256) void resolve_kernel(const float* __restrict__ z,
                                                      const float* __restrict__ emb,
                                                      const float* __restrict__ zz,
                                                      const float* __restrict__ ee,
                                                      const float* __restrict__ top8v,
                                                      const int* __restrict__ top8i,
                                                      const float* __restrict__ m3f,
                                                      int* __restrict__ idxf,
                                                      int* __restrict__ cnt,
                                                      int* __restrict__ rlist) {
    const int n = blockIdx.x * 256 + threadIdx.x;
    float v[8]; int id[8];
    {
        const float4 v0 = *reinterpret_cast<const float4*>(top8v + (size_t)n * 8);
        const float4 v1 = *reinterpret_cast<const float4*>(top8v + (size_t)n * 8 + 4);
        const int4   i0 = *reinterpret_cast<const int4*>(top8i + (size_t)n * 8);
        const int4   i1 = *reinterpret_cast<const int4*>(top8i + (size_t)n * 8 + 4);
        v[0]=v0.x; v[1]=v0.y; v[2]=v0.z; v[3]=v0.w; v[4]=v1.x; v[5]=v1.y; v[6]=v1.z; v[7]=v1.w;
        id[0]=i0.x; id[1]=i0.y; id[2]=i0.z; id[3]=i0.w; id[4]=i1.x; id[5]=i1.y; id[6]=i1.z; id[7]=i1.w;
    }
    const float lim = v[0] + EPSW;
    if (v[7] <= lim || m3f[n] <= lim) {      // union certificate failed
        idxf[n] = id[0];                     // provisional; rescan overwrites
        const int pos = atomicAdd(cnt, 1);
        rlist[pos] = n;
        return;
    }
    if (v[1] > lim) { idxf[n] = id[0]; return; }
    int ck[8]; int nc = 0;
    for (int j = 0; j < 8; ++j) if (v[j] <= lim) ck[nc++] = id[j];
    for (int a = 0; a < nc - 1; ++a)          // sort by k ascending
        for (int b2 = a + 1; b2 < nc; ++b2)
            if (ck[b2] < ck[a]) { int tmp = ck[a]; ck[a] = ck[b2]; ck[b2] = tmp; }
    float best = 0.0f; int bk = -1;
    for (int a = 0; a < nc; ++a) {
        const float d = np_dist(z, emb, zz, ee, n, ck[a]);
        if (bk < 0 || d < best) { best = d; bk = ck[a]; }
    }
    idxf[n] = bk;
}

// full np-exact rescan for flagged pixels (wave-parallel reduce, wide grid)
__global__ __launch_bounds__(256) void rescan_kernel(const float* __restrict__ z,
                                                     const float* __restrict__ emb,
                                                     const float* __restrict__ zz,
                                                     const float* __restrict__ ee,
                                                     const int* __restrict__ cnt,
                                                     const int* __restrict__ rlist,
                                                     int* __restrict__ idxf) {
#pragma clang fp contract(off)
    __shared__ float ls[DIM];
    __shared__ float wv[4];
    __shared__ int   wk[4];
    const int t = threadIdx.x;
    const int lane = t & 63, w = t >> 6;
    const int count = *cnt;
    for (int e = blockIdx.x; e < count; e += gridDim.x) {
        const int n = rlist[e];
        const int b = n >> 12, hw = n & (HW - 1);
        __syncthreads();   // protect ls/wv/wk from previous iteration's readers
        ls[t] = z[((size_t)(b * DIM + t)) * HW + hw];
        __syncthreads();
        const float zzn = zz[n];
        float bestd = 3.0e38f; int besti = 0x7fffffff;
        for (int j = 0; j < 16; ++j) {
            const int k = t + j * 256;
            const float* ep = emb + (size_t)k * DIM;
            float m = 0.0f;
            for (int i = 0; i < DIM; ++i) m = fmaf(ls[i], ep[i], m);
            const float d = (zzn + ee[k]) - 2.0f * m;
            if (d < bestd || (d == bestd && k < besti)) { bestd = d; besti = k; }
        }
        // wave-level lexicographic (d, k) min
        #pragma unroll
        for (int off = 32; off >= 1; off >>= 1) {
            const float od = __shfl_down(bestd, off, 64);
            const int   ok = __shfl_down(besti, off, 64);
            if (od < bestd || (od == bestd && ok < besti)) { bestd = od; besti = ok; }
        }
        if (lane == 0) { wv[w] = bestd; wk[w] = besti; }
        __syncthreads();
        if (t == 0) {
            float bd = wv[0]; int bi = wk[0];
            #pragma unroll
            for (int q = 1; q < 4; ++q)
                if (wv[q] < bd || (wv[q] == bd && wk[q] < bi)) { bd = wv[q]; bi = wk[q]; }
            idxf[n] = bi;
        }
    }
}

// gather z_q + idx output + loss partials
__global__ __launch_bounds__(256) void gather_kernel(const float* __restrict__ z,
                                                     const float* __restrict__ emb,
                                                     const int* __restrict__ idxf,
                                                     float* __restrict__ out,
                                                     float* __restrict__ part) {
    __shared__ int   idx_s[32];
    __shared__ float wred[4];
    const int tid = threadIdx.x;
    const int tx = tid & 31, ty = tid >> 5;
    const int m0 = blockIdx.x * 32;
    const int bimg = m0 >> 12, hw0 = m0 & (HW - 1);
    if (tid < 32) {
        const int ii = idxf[m0 + tid];
        idx_s[tid] = ii;
        out[NQ + m0 + tid] = (float)ii;
    }
    __syncthreads();
    float lsum = 0.0f;
    const size_t ebase = (size_t)idx_s[tx] * DIM;
    for (int it = 0; it < DIM / 8; ++it) {
        const int c = it * 8 + ty;
        const float e = emb[ebase + c];
        const size_t zoff = ((size_t)(bimg * DIM + c)) * HW + hw0 + tx;
        out[zoff] = e;
        const float diff = e - z[zoff];
        lsum += diff * diff;
    }
    #pragma unroll
    for (int off = 32; off >= 1; off >>= 1) lsum += __shfl_down(lsum, off, 64);
    if ((tid & 63) == 0) wred[tid >> 6] = lsum;
    __syncthreads();
    if (tid == 0) part[blockIdx.x] = wred[0] + wred[1] + wred[2] + wred[3];
}

__global__ __launch_bounds__(256) void loss_kernel(const float* __restrict__ part,
                                                   int nblk, float* __restrict__ out) {
    __shared__ float wred[4];
    const int tid = threadIdx.x;
    float s = 0.0f;
    for (int i = tid; i < nblk; i += 256) s += part[i];
    #pragma unroll
    for (int off = 32; off >= 1; off >>= 1) s += __shfl_down(s, off, 64);
    if ((tid & 63) == 0) wred[tid >> 6] = s;
    __syncthreads();
    if (tid == 0) {
        const float total = wred[0] + wred[1] + wred[2] + wred[3];
        out[NQ + NPIX] = 1.25f * total / 16777216.0f;
    }
}

// ---------------------------------------------------------------------------
// SAFE path: R3's proven fused VALU kernel (used when ws too small)
// ---------------------------------------------------------------------------
#define MP 32
#define KC 128
#define DC 32
__global__ __launch_bounds__(256) void safe_dist_kernel(const float* __restrict__ z,
                                                        const float* __restrict__ emb,
                                                        const float* __restrict__ ee,
                                                        const float* __restrict__ zz,
                                                        float* __restrict__ out,
                                                        float* __restrict__ part) {
    __shared__ float zs[MP][DIM + 4];
    __shared__ float est[DC][KC + 4];
    __shared__ float ee_s[KC];
    __shared__ float zz_s[MP];
    __shared__ float red_v[MP][33];
    __shared__ int   red_i[MP][33];
    __shared__ int   idx_s[MP];
    __shared__ float wred[4];

    const int tid = threadIdx.x;
    const int tx = tid & 31, ty = tid >> 5;
    const int m0 = blockIdx.x * MP;
    const int bimg = m0 >> 12, hw0 = m0 & (HW - 1);

    for (int c = ty; c < DIM; c += 8)
        zs[tx][c] = z[((size_t)(bimg * DIM + c)) * HW + hw0 + tx];
    if (tid < MP) zz_s[tid] = zz[m0 + tid];

    float minv[4]; int mini[4];
    #pragma unroll
    for (int p = 0; p < 4; ++p) { minv[p] = 3.0e38f; mini[p] = 0; }
    const int rl = tid >> 3, cl = tid & 7;

    for (int kc = 0; kc < KCODES / KC; ++kc) {
        float acc[4][4];
        #pragma unroll
        for (int p = 0; p < 4; ++p)
            #pragma unroll
            for (int q = 0; q < 4; ++q) acc[p][q] = 0.0f;
        for (int dc = 0; dc < DIM / DC; ++dc) {
            __syncthreads();
            if (dc == 0 && tid < KC) ee_s[tid] = ee[kc * KC + tid];
            #pragma unroll
            for (int it = 0; it < 4; ++it) {
                const int kl = it * 32 + rl;
                const float4 v = *reinterpret_cast<const float4*>(
                    emb + (size_t)(kc * KC + kl) * DIM + dc * DC + cl * 4);
                est[cl * 4 + 0][kl] = v.x;
                est[cl * 4 + 1][kl] = v.y;
                est[cl * 4 + 2][kl] = v.z;
                est[cl * 4 + 3][kl] = v.w;
            }
            __syncthreads();
            #pragma unroll
            for (int g = 0; g < DC / 4; ++g) {
                float4 zr[4];
                #pragma unroll
                for (int p = 0; p < 4; ++p)
                    zr[p] = *reinterpret_cast<const float4*>(&zs[ty * 4 + p][dc * DC + g * 4]);
                float4 er[4];
                #pragma unroll
                for (int j = 0; j < 4; ++j)
                    er[j] = *reinterpret_cast<const float4*>(&est[g * 4 + j][tx * 4]);
                #pragma unroll
                for (int p = 0; p < 4; ++p) {
                    acc[p][0] = fmaf(zr[p].x, er[0].x, acc[p][0]);
                    acc[p][0] = fmaf(zr[p].y, er[1].x, acc[p][0]);
                    acc[p][0] = fmaf(zr[p].z, er[2].x, acc[p][0]);
                    acc[p][0] = fmaf(zr[p].w, er[3].x, acc[p][0]);
                    acc[p][1] = fmaf(zr[p].x, er[0].y, acc[p][1]);
                    acc[p][1] = fmaf(zr[p].y, er[1].y, acc[p][1]);
                    acc[p][1] = fmaf(zr[p].z, er[2].y, acc[p][1]);
                    acc[p][1] = fmaf(zr[p].w, er[3].y, acc[p][1]);
                    acc[p][2] = fmaf(zr[p].x, er[0].z, acc[p][2]);
                    acc[p][2] = fmaf(zr[p].y, er[1].z, acc[p][2]);
                    acc[p][2] = fmaf(zr[p].z, er[2].z, acc[p][2]);
                    acc[p][2] = fmaf(zr[p].w, er[3].z, acc[p][2]);
                    acc[p][3] = fmaf(zr[p].x, er[0].w, acc[p][3]);
                    acc[p][3] = fmaf(zr[p].y, er[1].w, acc[p][3]);
                    acc[p][3] = fmaf(zr[p].z, er[2].w, acc[p][3]);
                    acc[p][3] = fmaf(zr[p].w, er[3].w, acc[p][3]);
                }
            }
        }
        #pragma unroll
        for (int q = 0; q < 4; ++q) {
            const int kg = kc * KC + tx * 4 + q;
            const float en = ee_s[tx * 4 + q];
            #pragma unroll
            for (int p = 0; p < 4; ++p) {
                const float t = zz_s[ty * 4 + p] + en;
                const float d = t - 2.0f * acc[p][q];
                if (d < minv[p]) { minv[p] = d; mini[p] = kg; }
            }
        }
    }
    #pragma unroll
    for (int p = 0; p < 4; ++p) {
        red_v[ty * 4 + p][tx] = minv[p];
        red_i[ty * 4 + p][tx] = mini[p];
    }
    __syncthreads();
    if (tid < MP) {
        float bvv = red_v[tid][0]; int bii = red_i[tid][0];
        for (int q = 1; q < 32; ++q) {
            const float vq = red_v[tid][q]; const int iq = red_i[tid][q];
            if (vq < bvv || (vq == bvv && iq < bii)) { bvv = vq; bii = iq; }
        }
        idx_s[tid] = bii;
        out[NQ + m0 + tid] = (float)bii;
    }
    __syncthreads();
    float lsum = 0.0f;
    const size_t ebase = (size_t)idx_s[tx] * DIM;
    for (int it = 0; it < DIM / 8; ++it) {
        const int c = it * 8 + ty;
        const float e = emb[ebase + c];
        out[((size_t)(bimg * DIM + c)) * HW + hw0 + tx] = e;
        const float diff = e - zs[tx][c];
        lsum += diff * diff;
    }
    #pragma unroll
    for (int off = 32; off >= 1; off >>= 1) lsum += __shfl_down(lsum, off, 64);
    if ((tid & 63) == 0) wred[tid >> 6] = lsum;
    __syncthreads();
    if (tid == 0) part[blockIdx.x] = wred[0] + wred[1] + wred[2] + wred[3];
}

// ---------------------------------------------------------------------------
extern "C" void kernel_launch(void* const* d_in, const int* in_sizes, int n_in,
                              void* d_out, int out_size, void* d_ws, size_t ws_size,
                              hipStream_t stream) {
    const float* z   = (const float*)d_in[0];
    const float* emb = (const float*)d_in[1];
    float* out = (float*)d_out;
    char*  ws  = (char*)d_ws;

    float* zz   = (float*)(ws + 0);            // 256K
    float* ee   = (float*)(ws + 262144);       // 16K
    float* part = (float*)(ws + 278528);       // 8K
    int*   cnt  = (int*)  (ws + 286720);       // 4K
    int*   rlst = (int*)  (ws + 290816);       // 256K
    int*   idxf = (int*)  (ws + 552960);       // 256K
    float* t8v  = (float*)(ws + 1048576);      // 2M
    int*   t8i  = (int*)  (ws + 3145728);      // 2M
    ushort* eh  = (ushort*)(ws + 5242880);     // 2M (hi only)
    ushort* zh  = (ushort*)(ws + 7340032);     // 32M (hi only) -> ends 40894464
    float* m3f  = (float*)(ws + 40894464);     // 256K
    const size_t REQ = 74448896;               // ~71 MB (granted in R4-R17)

    ee_np_kernel<<<KCODES / 256, 256, 0, stream>>>(emb, ee);
    zz_np_kernel<<<NPIX / 256, 256, 0, stream>>>(z, zz);

    if (ws_size >= REQ) {
        hipMemsetAsync(cnt, 0, 4, stream);
        cvt_emb_kernel<<<KCODES / 4, 256, 0, stream>>>(emb, eh);
        cvt_z_kernel<<<4096, 256, 0, stream>>>(z, zh);
        gemm_kernel<<<NPIX / 64, 256, 0, stream>>>(eh, zh, ee, zz, t8v, t8i, m3f);
        resolve_kernel<<<NPIX / 256, 256, 0, stream>>>(z, emb, zz, ee, t8v, t8i, m3f, idxf, cnt, rlst);
        rescan_kernel<<<2048, 256, 0, stream>>>(z, emb, zz, ee, cnt, rlst, idxf);
        gather_kernel<<<NPIX / 32, 256, 0, stream>>>(z, emb, idxf, out, part);
        loss_kernel<<<1, 256, 0, stream>>>(part, NPIX / 32, out);
    } else {
        safe_dist_kernel<<<NPIX / MP, 256, 0, stream>>>(z, emb, ee, zz, out, part);
        loss_kernel<<<1, 256, 0, stream>>>(part, NPIX / MP, out);
    }
}

// Round 19
// 520.277 us; speedup vs baseline: 1.4475x; 1.4475x over previous
//
#include <hip/hip_runtime.h>
#include <math.h>

#define KCODES 4096
#define DIM    256
#define HW     4096
#define NPIX   65536
#define NQ     16777216   // 16*256*64*64
#define EPSW   3.0e-4f    // hh-only scan: eps_max ~1.25e-4 rigorous; EPSW >= 2*eps

typedef _Float16 f16x8 __attribute__((ext_vector_type(8)));
typedef float    f32x4 __attribute__((ext_vector_type(4)));

// XOR swizzle on tile-local byte offset (within 8KB chunk of 128 rows x 64B).
#define SWZ(x) ((x) ^ ((((x) >> 6) & 7) << 4))

static __device__ __forceinline__ void gld16(const void* g, void* l) {
    __builtin_amdgcn_global_load_lds(
        (const __attribute__((address_space(1))) void*)g,
        (__attribute__((address_space(3))) void*)l, 16, 0, 0);
}

// top4 insert, strict < (ascending-k feed => lowest k kept on ties; a tie-drop
// at V[3] is covered by the m3<=lim rescan flag)
#define INS4(V, I, dd, kk) do { \
  if ((dd) < V[3]) { \
    if ((dd) < V[1]) { \
      V[3]=V[2]; I[3]=I[2]; V[2]=V[1]; I[2]=I[1]; \
      if ((dd) < V[0]) { V[1]=V[0]; I[1]=I[0]; V[0]=(dd); I[0]=(kk); } \
      else             { V[1]=(dd); I[1]=(kk); } \
    } else { \
      if ((dd) < V[2]) { V[3]=V[2]; I[3]=I[2]; V[2]=(dd); I[2]=(kk); } \
      else             { V[3]=(dd); I[3]=(kk); } \
    } } } while(0)

// top8 insert (merge-time only), strict <; tie-drops at V[7] covered by flag
#define INS8(V, I, dd, kk) do { \
  if ((dd) < V[7]) { \
    if ((dd) < V[3]) { \
      V[7]=V[6];I[7]=I[6];V[6]=V[5];I[6]=I[5];V[5]=V[4];I[5]=I[4];V[4]=V[3];I[4]=I[3]; \
      if ((dd) < V[1]) { \
        V[3]=V[2];I[3]=I[2];V[2]=V[1];I[2]=I[1]; \
        if ((dd) < V[0]) { V[1]=V[0];I[1]=I[0];V[0]=(dd);I[0]=(kk); } \
        else             { V[1]=(dd);I[1]=(kk); } \
      } else { \
        if ((dd) < V[2]) { V[3]=V[2];I[3]=I[2];V[2]=(dd);I[2]=(kk); } \
        else             { V[3]=(dd);I[3]=(kk); } \
      } \
    } else { \
      if ((dd) < V[5]) { \
        V[7]=V[6];I[7]=I[6];V[6]=V[5];I[6]=I[5]; \
        if ((dd) < V[4]) { V[5]=V[4];I[5]=I[4];V[4]=(dd);I[4]=(kk); } \
        else             { V[5]=(dd);I[5]=(kk); } \
      } else { \
        if ((dd) < V[6]) { V[7]=V[6];I[7]=I[6];V[6]=(dd);I[6]=(kk); } \
        else             { V[7]=(dd);I[7]=(kk); } \
      } \
    } } } while(0)

// ---------------------------------------------------------------------------
// np-exact helpers (bit-replicate numpy f32 semantics — proven in R3)
// ---------------------------------------------------------------------------
__global__ __launch_bounds__(256) void ee_np_kernel(const float* __restrict__ emb,
                                                    float* __restrict__ ee) {
#pragma clang fp contract(off)
    const int k = blockIdx.x * 256 + threadIdx.x;
    const float* a = emb + (size_t)k * DIM;
    float res[2];
    #pragma unroll
    for (int h = 0; h < 2; ++h) {
        const float* b = a + h * 128;
        float r[8];
        #pragma unroll
        for (int j = 0; j < 8; ++j) { const float x = b[j]; r[j] = x * x; }
        for (int i = 8; i < 128; i += 8) {
            #pragma unroll
            for (int j = 0; j < 8; ++j) { const float x = b[i + j]; r[j] += x * x; }
        }
        res[h] = ((r[0] + r[1]) + (r[2] + r[3])) + ((r[4] + r[5]) + (r[6] + r[7]));
    }
    ee[k] = res[0] + res[1];
}

// standalone zz (SAFE path only; fast path computes zz inside cvt_z)
__global__ __launch_bounds__(256) void zz_np_kernel(const float* __restrict__ z,
                                                    float* __restrict__ zz) {
#pragma clang fp contract(off)
    const int n  = blockIdx.x * 256 + threadIdx.x;
    const int b  = n >> 12;
    const int hw = n & (HW - 1);
    const float* base = z + (size_t)b * DIM * HW + hw;
    float res[2];
    #pragma unroll
    for (int h = 0; h < 2; ++h) {
        const float* p = base + (size_t)(h * 128) * HW;
        float r[8];
        #pragma unroll
        for (int j = 0; j < 8; ++j) { const float x = p[(size_t)j * HW]; r[j] = x * x; }
        for (int i = 8; i < 128; i += 8) {
            #pragma unroll
            for (int j = 0; j < 8; ++j) { const float x = p[(size_t)(i + j) * HW]; r[j] += x * x; }
        }
        res[h] = ((r[0] + r[1]) + (r[2] + r[3])) + ((r[4] + r[5]) + (r[6] + r[7]));
    }
    zz[n] = res[0] + res[1];
}

__device__ float np_dist(const float* __restrict__ z, const float* __restrict__ emb,
                         const float* __restrict__ zz, const float* __restrict__ ee,
                         int n, int k) {
    const int b = n >> 12, hw = n & (HW - 1);
    const float* zp = z + (size_t)b * DIM * HW + hw;
    const float* ep = emb + (size_t)k * DIM;
    float m = 0.0f;
    for (int i = 0; i < DIM; ++i) m = fmaf(zp[(size_t)i * HW], ep[i], m);
    const float t = zz[n] + ee[k];
    return t - 2.0f * m;
}

// ---------------------------------------------------------------------------
// FAST path kernels
// ---------------------------------------------------------------------------
// emb -> tiled fp16 HI only, scaled by 4096 (exact pow2), PRE-SWIZZLED.
__global__ __launch_bounds__(256) void cvt_emb_kernel(const float* __restrict__ emb,
                                                      ushort* __restrict__ eh) {
    const int t = threadIdx.x;
    const int k = blockIdx.x * 4 + (t >> 6);
    const int seg = t & 63;                       // 4-elem segment
    const float4 v = *reinterpret_cast<const float4*>(emb + (size_t)k * DIM + seg * 4);
    union H4 { _Float16 h[4]; short4 s; } uh;
    const float vv[4] = {v.x, v.y, v.z, v.w};
    #pragma unroll
    for (int j = 0; j < 4; ++j) uh.h[j] = (_Float16)(vv[j] * 4096.0f);
    const int s = seg >> 3;
    const int y  = (k & 127) * 64 + (seg & 7) * 8;        // logical byte in 8KB chunk
    const int ys = y ^ ((k & 7) << 4);                    // pre-swizzled
    const size_t addr = (size_t)(k >> 7) * 32768 + s * 4096 + (ys >> 1);
    *reinterpret_cast<short4*>(eh + addr) = uh.s;
}

// z (NCHW) -> transposed tiled fp16 HI [pixel][dim], PRE-SWIZZLED.
// FUSED: also computes zz (numpy pairwise-8, bit-exact) from the staged tile.
// Block = 64 pixels x ALL 256 channels (grid 1024).
__global__ __launch_bounds__(256) void cvt_z_kernel(const float* __restrict__ z,
                                                    ushort* __restrict__ zh,
                                                    float* __restrict__ zz) {
#pragma clang fp contract(off)
    __shared__ float ls[256][65];   // [channel][pixel], +1 pad
    const int t = threadIdx.x;
    const int bid = blockIdx.x;
    const int b = bid >> 6, hh = bid & 63;
    const int col = t & 63, r0 = t >> 6;
    #pragma unroll
    for (int i = 0; i < 64; ++i) {
        const int c = i * 4 + r0;
        ls[c][col] = z[((size_t)(b * DIM + c)) * HW + hh * 64 + col];
    }
    __syncthreads();

    // zz for the 64 pixels (numpy pairwise order, bit-exact)
    if (t < 64) {
        float res[2];
        #pragma unroll
        for (int h = 0; h < 2; ++h) {
            const int base = h * 128;
            float r[8];
            #pragma unroll
            for (int j = 0; j < 8; ++j) { const float x = ls[base + j][t]; r[j] = x * x; }
            for (int i = 8; i < 128; i += 8) {
                #pragma unroll
                for (int j = 0; j < 8; ++j) { const float x = ls[base + i + j][t]; r[j] += x * x; }
            }
            res[h] = ((r[0] + r[1]) + (r[2] + r[3])) + ((r[4] + r[5]) + (r[6] + r[7]));
        }
        zz[b * HW + hh * 64 + t] = res[0] + res[1];
    }

    // fp16 conversion + pre-swizzled tiled stores (each thread: 64 channels)
    const int pxl = t >> 2, cseg = t & 3;
    const int px = b * HW + hh * 64 + pxl;
    const size_t chunkb = (size_t)(px >> 7) * 32768;
    const int msk = (px & 7) << 4;
    #pragma unroll
    for (int g = 0; g < 4; ++g) {
        const int cb = cseg * 64 + g * 16;     // channel base (16 channels)
        union H8 { _Float16 h[8]; int4 v; } ha, hb;
        #pragma unroll
        for (int j = 0; j < 16; ++j) {
            const float val = ls[cb + j][pxl];
            if (j < 8) ha.h[j] = (_Float16)val;
            else       hb.h[j - 8] = (_Float16)val;
        }
        const int sg = cb >> 5;                                // dim-subchunk 0..7
        const int y1 = (px & 127) * 64 + ((cb >> 4) & 1) * 32; // byte in 8KB chunk
        *reinterpret_cast<int4*>(zh + chunkb + sg * 4096 + ((y1 ^ msk) >> 1))        = ha.v;
        *reinterpret_cast<int4*>(zh + chunkb + sg * 4096 + (((y1 + 16) ^ msk) >> 1)) = hb.v;
    }
}

// MFMA distance pass (hh-only): block = 64 pixels x 4096 codes. (R16-proven)
// z fragments REGISTER-RESIDENT; code chunks (16KB) double-buffered via gld16.
__global__ __launch_bounds__(256, 3) void gemm_kernel(const ushort* __restrict__ eh,
                                                      const ushort* __restrict__ zh,
                                                      const float* __restrict__ ee,
                                                      const float* __restrict__ zz,
                                                      float* __restrict__ top8v,
                                                      int* __restrict__ top8i,
                                                      float* __restrict__ m3f) {
    __shared__ __align__(16) char et[2][16384];  // code dbuf: 2 x (2 s-chunks)

    const int t = threadIdx.x;
    const int lane = t & 63, w = t >> 6, wr = w >> 1, wc = w & 1;
    const int l15 = lane & 15, l4 = lane >> 4;
    const int bid = blockIdx.x;
    const int px0 = bid * 64;
    const int lo = t * 16;            // per-lane linear byte offset within 4KB round
    const int wb = w * 1024;          // wave-uniform LDS base
    const char* ehB = (const char*)eh;

    // ---- load z fragments into registers (once) ----
    f16x8 zr[2][8];
    {
        const size_t chunk = (size_t)(bid >> 1) * 32768;   // halfs
        #pragma unroll
        for (int ni = 0; ni < 2; ++ni) {
            const int lr = (bid & 1) * 64 + wc * 32 + ni * 16 + l15;  // row in 128-chunk
            const int ro = SWZ(lr * 64 + l4 * 16) >> 1;               // halfs
            #pragma unroll
            for (int s = 0; s < 8; ++s)
                zr[ni][s] = *reinterpret_cast<const f16x8*>(zh + chunk + s * 4096 + ro);
        }
    }
    float zzr[2];
    #pragma unroll
    for (int ni = 0; ni < 2; ++ni) zzr[ni] = zz[px0 + wc * 32 + ni * 16 + l15];

    // per-lane code-fragment byte offsets within an 8KB dim-subchunk
    int aoff[4];
    #pragma unroll
    for (int mi = 0; mi < 4; ++mi)
        aoff[mi] = SWZ((wr * 64 + mi * 16 + l15) * 64 + l4 * 16);

    // ---- stage first 16KB code step ----
    #pragma unroll
    for (int r = 0; r < 4; ++r)
        gld16(ehB + r * 4096 + lo, et[0] + r * 4096 + wb);
    __syncthreads();

    float Tv[2][4]; int Ti[2][4];
    #pragma unroll
    for (int ni = 0; ni < 2; ++ni)
        #pragma unroll
        for (int j = 0; j < 4; ++j) { Tv[ni][j] = 3.0e38f; Ti[ni][j] = 0; }

    for (int p = 0; p < 32; ++p) {
        float eer[4][4];
        #pragma unroll
        for (int mi = 0; mi < 4; ++mi)
            #pragma unroll
            for (int r = 0; r < 4; ++r)
                eer[mi][r] = ee[p * 128 + wr * 64 + mi * 16 + l4 * 4 + r];

        f32x4 acc[4][2];
        #pragma unroll
        for (int mi = 0; mi < 4; ++mi)
            #pragma unroll
            for (int ni = 0; ni < 2; ++ni)
                acc[mi][ni] = (f32x4){0.0f, 0.0f, 0.0f, 0.0f};

        #pragma unroll
        for (int st = 0; st < 4; ++st) {
            const int cur = st & 1;            // compile-time buffer parity
            // prefetch next 16KB step into the other buffer
            if (st < 3 || p < 31) {
                const size_t nb = ((size_t)(p * 4 + st) + 1) * 16384;
                #pragma unroll
                for (int r = 0; r < 4; ++r)
                    gld16(ehB + nb + r * 4096 + lo, et[cur ^ 1] + r * 4096 + wb);
            }
            #pragma unroll
            for (int sp = 0; sp < 2; ++sp) {
                const int sg = st * 2 + sp;    // global s 0..7
                f16x8 aH[4];
                #pragma unroll
                for (int mi = 0; mi < 4; ++mi)
                    aH[mi] = *reinterpret_cast<const f16x8*>(et[cur] + sp * 8192 + aoff[mi]);
                #pragma unroll
                for (int mi = 0; mi < 4; ++mi)
                    #pragma unroll
                    for (int ni = 0; ni < 2; ++ni)
                        acc[mi][ni] = __builtin_amdgcn_mfma_f32_16x16x32_f16(aH[mi], zr[ni][sg], acc[mi][ni], 0, 0, 0);
            }
            __syncthreads();   // et[cur] reads done; et[cur^1] loads landed
        }
        // epilogue: d = fl((zz+ee) - acc*2^-11), per-thread top4 (ascending k)
        #pragma unroll
        for (int ni = 0; ni < 2; ++ni) {
            const float zzc = zzr[ni];
            #pragma unroll
            for (int mi = 0; mi < 4; ++mi) {
                #pragma unroll
                for (int r = 0; r < 4; ++r) {
                    const float tt = zzc + eer[mi][r];
                    const float d = fmaf(acc[mi][ni][r], -4.8828125e-4f, tt);
                    const int k = p * 128 + wr * 64 + mi * 16 + l4 * 4 + r;
                    INS4(Tv[ni], Ti[ni], d, k);
                }
            }
        }
    }

    // merge arrays alias the code buffers (dead after the loop)
    float (*mv)[64][8]  = reinterpret_cast<float (*)[64][8]>(&et[0][0]);
    int   (*mi_)[64][8] = reinterpret_cast<int (*)[64][8]>(&et[0][8192]);
    float (*m3s)[64]    = reinterpret_cast<float (*)[64]>(&et[1][0]);

    // per-ni: expand top4 -> top8, merge across l4 lanes (xor16/xor32), track m3
    #pragma unroll
    for (int ni = 0; ni < 2; ++ni) {
        float fv[8]; int fi[8];
        #pragma unroll
        for (int j = 0; j < 4; ++j) { fv[j] = Tv[ni][j]; fi[j] = Ti[ni][j]; }
        #pragma unroll
        for (int j = 4; j < 8; ++j) { fv[j] = 3.0e38f; fi[j] = 0; }
        float m3 = Tv[ni][3];          // pre-merge thread-local 4th best
        #pragma unroll
        for (int m = 16; m <= 32; m <<= 1) {
            float ov[8]; int oi[8];
            #pragma unroll
            for (int j = 0; j < 8; ++j) {
                ov[j] = __shfl_xor(fv[j], m, 64);
                oi[j] = __shfl_xor(fi[j], m, 64);
            }
            const float om = __shfl_xor(m3, m, 64);
            #pragma unroll
            for (int j = 0; j < 8; ++j) INS8(fv, fi, ov[j], oi[j]);
            m3 = fminf(m3, om);
        }
        if (lane < 16) {
            const int c = wc * 32 + ni * 16 + lane;
            #pragma unroll
            for (int j = 0; j < 8; ++j) { mv[wr][c][j] = fv[j]; mi_[wr][c][j] = fi[j]; }
            m3s[wr][c] = m3;
        }
    }
    __syncthreads();
    if (t < 64) {
        float fv[8]; int fi[8];
        #pragma unroll
        for (int j = 0; j < 8; ++j) { fv[j] = mv[0][t][j]; fi[j] = mi_[0][t][j]; }
        #pragma unroll
        for (int j = 0; j < 8; ++j) INS8(fv, fi, mv[1][t][j], mi_[1][t][j]);
        const float m3 = fminf(m3s[0][t], m3s[1][t]);
        const int px = px0 + t;
        *reinterpret_cast<float4*>(top8v + (size_t)px * 8)     = make_float4(fv[0], fv[1], fv[2], fv[3]);
        *reinterpret_cast<float4*>(top8v + (size_t)px * 8 + 4) = make_float4(fv[4], fv[5], fv[6], fv[7]);
        *reinterpret_cast<int4*>(top8i + (size_t)px * 8)       = make_int4(fi[0], fi[1], fi[2], fi[3]);
        *reinterpret_cast<int4*>(top8i + (size_t)px * 8 + 4)   = make_int4(fi[4], fi[5], fi[6], fi[7]);
        m3f[px] = m3;
    }
}

// resolve: shortcut / np-exact candidate re-evaluation / rescan flagging
__global__ __launch_bounds__(256) void resolve_kernel(const float* __restrict__ z,
                                                      const float* __restrict__ emb,
                                                      const float* __restrict__ zz,
                                                      const float* __restrict__ ee,
                                                      const float* __restrict__ top8v,
                                                      const int* __restrict__ top8i,
                                                      const float* __restrict__ m3f,
                                                      int* __restrict__ idxf,
                                                      int* __restrict__ cnt,
                                                      int* __restrict__ rlist) {
    const int n = blockIdx.x * 256 + threadIdx.x;
    float v[8]; int id[8];
    {
        const float4 v0 = *reinterpret_cast<const float4*>(top8v + (size_t)n * 8);
        const float4 v1 = *reinterpret_cast<const float4*>(top8v + (size_t)n * 8 + 4);
        const int4   i0 = *reinterpret_cast<const int4*>(top8i + (size_t)n * 8);
        const int4   i1 = *reinterpret_cast<const int4*>(top8i + (size_t)n * 8 + 4);
        v[0]=v0.x; v[1]=v0.y; v[2]=v0.z; v[3]=v0.w; v[4]=v1.x; v[5]=v1.y; v[6]=v1.z; v[7]=v1.w;
        id[0]=i0.x; id[1]=i0.y; id[2]=i0.z; id[3]=i0.w; id[4]=i1.x; id[5]=i1.y; id[6]=i1.z; id[7]=i1.w;
    }
    const float lim = v[0] + EPSW;
    if (v[7] <= lim || m3f[n] <= lim) {      // union certificate failed
        idxf[n] = id[0];                     // provisional; rescan overwrites
        const int pos = atomicAdd(cnt, 1);
        rlist[pos] = n;
        return;
    }
    if (v[1] > lim) { idxf[n] = id[0]; return; }
    int ck[8]; int nc = 0;
    for (int j = 0; j < 8; ++j) if (v[j] <= lim) ck[nc++] = id[j];
    for (int a = 0; a < nc - 1; ++a)          // sort by k ascending
        for (int b2 = a + 1; b2 < nc; ++b2)
            if (ck[b2] < ck[a]) { int tmp = ck[a]; ck[a] = ck[b2]; ck[b2] = tmp; }
    float best = 0.0f; int bk = -1;
    for (int a = 0; a < nc; ++a) {
        const float d = np_dist(z, emb, zz, ee, n, ck[a]);
        if (bk < 0 || d < best) { best = d; bk = ck[a]; }
    }
    idxf[n] = bk;
}

// full np-exact rescan for flagged pixels (wave-parallel reduce, wide grid)
__global__ __launch_bounds__(256) void rescan_kernel(const float* __restrict__ z,
                                                     const float* __restrict__ emb,
                                                     const float* __restrict__ zz,
                                                     const float* __restrict__ ee,
                                                     const int* __restrict__ cnt,
                                                     const int* __restrict__ rlist,
                                                     int* __restrict__ idxf) {
#pragma clang fp contract(off)
    __shared__ float ls[DIM];
    __shared__ float wv[4];
    __shared__ int   wk[4];
    const int t = threadIdx.x;
    const int lane = t & 63, w = t >> 6;
    const int count = *cnt;
    for (int e = blockIdx.x; e < count; e += gridDim.x) {
        const int n = rlist[e];
        const int b = n >> 12, hw = n & (HW - 1);
        __syncthreads();   // protect ls/wv/wk from previous iteration's readers
        ls[t] = z[((size_t)(b * DIM + t)) * HW + hw];
        __syncthreads();
        const float zzn = zz[n];
        float bestd = 3.0e38f; int besti = 0x7fffffff;
        for (int j = 0; j < 16; ++j) {
            const int k = t + j * 256;
            const float* ep = emb + (size_t)k * DIM;
            float m = 0.0f;
            for (int i = 0; i < DIM; ++i) m = fmaf(ls[i], ep[i], m);
            const float d = (zzn + ee[k]) - 2.0f * m;
            if (d < bestd || (d == bestd && k < besti)) { bestd = d; besti = k; }
        }
        // wave-level lexicographic (d, k) min
        #pragma unroll
        for (int off = 32; off >= 1; off >>= 1) {
            const float od = __shfl_down(bestd, off, 64);
            const int   ok = __shfl_down(besti, off, 64);
            if (od < bestd || (od == bestd && ok < besti)) { bestd = od; besti = ok; }
        }
        if (lane == 0) { wv[w] = bestd; wk[w] = besti; }
        __syncthreads();
        if (t == 0) {
            float bd = wv[0]; int bi = wk[0];
            #pragma unroll
            for (int q = 1; q < 4; ++q)
                if (wv[q] < bd || (wv[q] == bd && wk[q] < bi)) { bd = wv[q]; bi = wk[q]; }
            idxf[n] = bi;
        }
    }
}

// gather z_q + idx output + loss partials; emb rows STAGED in LDS (coalesced)
__global__ __launch_bounds__(256) void gather_kernel(const float* __restrict__ z,
                                                     const float* __restrict__ emb,
                                                     const int* __restrict__ idxf,
                                                     float* __restrict__ out,
                                                     float* __restrict__ part) {
    __shared__ int   idx_s[32];
    __shared__ float es[32][257];
    __shared__ float wred[4];
    const int tid = threadIdx.x;
    const int tx = tid & 31, ty = tid >> 5;
    const int m0 = blockIdx.x * 32;
    const int bimg = m0 >> 12, hw0 = m0 & (HW - 1);
    if (tid < 32) {
        const int ii = idxf[m0 + tid];
        idx_s[tid] = ii;
        out[NQ + m0 + tid] = (float)ii;
    }
    __syncthreads();
    // stage the 32 gathered emb rows (each iter: one coalesced 1KB read)
    for (int r = 0; r < 32; ++r)
        es[r][tid] = emb[(size_t)idx_s[r] * DIM + tid];
    __syncthreads();
    float lsum = 0.0f;
    for (int it = 0; it < DIM / 8; ++it) {
        const int c = it * 8 + ty;
        const float e = es[tx][c];
        const size_t zoff = ((size_t)(bimg * DIM + c)) * HW + hw0 + tx;
        out[zoff] = e;
        const float diff = e - z[zoff];
        lsum += diff * diff;
    }
    #pragma unroll
    for (int off = 32; off >= 1; off >>= 1) lsum += __shfl_down(lsum, off, 64);
    if ((tid & 63) == 0) wred[tid >> 6] = lsum;
    __syncthreads();
    if (tid == 0) part[blockIdx.x] = wred[0] + wred[1] + wred[2] + wred[3];
}

__global__ __launch_bounds__(256) void loss_kernel(const float* __restrict__ part,
                                                   int nblk, float* __restrict__ out) {
    __shared__ float wred[4];
    const int tid = threadIdx.x;
    float s = 0.0f;
    for (int i = tid; i < nblk; i += 256) s += part[i];
    #pragma unroll
    for (int off = 32; off >= 1; off >>= 1) s += __shfl_down(s, off, 64);
    if ((tid & 63) == 0) wred[tid >> 6] = s;
    __syncthreads();
    if (tid == 0) {
        const float total = wred[0] + wred[1] + wred[2] + wred[3];
        out[NQ + NPIX] = 1.25f * total / 16777216.0f;
    }
}

// ---------------------------------------------------------------------------
// SAFE path: R3's proven fused VALU kernel (used when ws too small)
// ---------------------------------------------------------------------------
#define MP 32
#define KC 128
#define DC 32
__global__ __launch_bounds__(256) void safe_dist_kernel(const float* __restrict__ z,
                                                        const float* __restrict__ emb,
                                                        const float* __restrict__ ee,
                                                        const float* __restrict__ zz,
                                                        float* __restrict__ out,
                                                        float* __restrict__ part) {
    __shared__ float zs[MP][DIM + 4];
    __shared__ float est[DC][KC + 4];
    __shared__ float ee_s[KC];
    __shared__ float zz_s[MP];
    __shared__ float red_v[MP][33];
    __shared__ int   red_i[MP][33];
    __shared__ int   idx_s[MP];
    __shared__ float wred[4];

    const int tid = threadIdx.x;
    const int tx = tid & 31, ty = tid >> 5;
    const int m0 = blockIdx.x * MP;
    const int bimg = m0 >> 12, hw0 = m0 & (HW - 1);

    for (int c = ty; c < DIM; c += 8)
        zs[tx][c] = z[((size_t)(bimg * DIM + c)) * HW + hw0 + tx];
    if (tid < MP) zz_s[tid] = zz[m0 + tid];

    float minv[4]; int mini[4];
    #pragma unroll
    for (int p = 0; p < 4; ++p) { minv[p] = 3.0e38f; mini[p] = 0; }
    const int rl = tid >> 3, cl = tid & 7;

    for (int kc = 0; kc < KCODES / KC; ++kc) {
        float acc[4][4];
        #pragma unroll
        for (int p = 0; p < 4; ++p)
            #pragma unroll
            for (int q = 0; q < 4; ++q) acc[p][q] = 0.0f;
        for (int dc = 0; dc < DIM / DC; ++dc) {
            __syncthreads();
            if (dc == 0 && tid < KC) ee_s[tid] = ee[kc * KC + tid];
            #pragma unroll
            for (int it = 0; it < 4; ++it) {
                const int kl = it * 32 + rl;
                const float4 v = *reinterpret_cast<const float4*>(
                    emb + (size_t)(kc * KC + kl) * DIM + dc * DC + cl * 4);
                est[cl * 4 + 0][kl] = v.x;
                est[cl * 4 + 1][kl] = v.y;
                est[cl * 4 + 2][kl] = v.z;
                est[cl * 4 + 3][kl] = v.w;
            }
            __syncthreads();
            #pragma unroll
            for (int g = 0; g < DC / 4; ++g) {
                float4 zr[4];
                #pragma unroll
                for (int p = 0; p < 4; ++p)
                    zr[p] = *reinterpret_cast<const float4*>(&zs[ty * 4 + p][dc * DC + g * 4]);
                float4 er[4];
                #pragma unroll
                for (int j = 0; j < 4; ++j)
                    er[j] = *reinterpret_cast<const float4*>(&est[g * 4 + j][tx * 4]);
                #pragma unroll
                for (int p = 0; p < 4; ++p) {
                    acc[p][0] = fmaf(zr[p].x, er[0].x, acc[p][0]);
                    acc[p][0] = fmaf(zr[p].y, er[1].x, acc[p][0]);
                    acc[p][0] = fmaf(zr[p].z, er[2].x, acc[p][0]);
                    acc[p][0] = fmaf(zr[p].w, er[3].x, acc[p][0]);
                    acc[p][1] = fmaf(zr[p].x, er[0].y, acc[p][1]);
                    acc[p][1] = fmaf(zr[p].y, er[1].y, acc[p][1]);
                    acc[p][1] = fmaf(zr[p].z, er[2].y, acc[p][1]);
                    acc[p][1] = fmaf(zr[p].w, er[3].y, acc[p][1]);
                    acc[p][2] = fmaf(zr[p].x, er[0].z, acc[p][2]);
                    acc[p][2] = fmaf(zr[p].y, er[1].z, acc[p][2]);
                    acc[p][2] = fmaf(zr[p].z, er[2].z, acc[p][2]);
                    acc[p][2] = fmaf(zr[p].w, er[3].z, acc[p][2]);
                    acc[p][3] = fmaf(zr[p].x, er[0].w, acc[p][3]);
                    acc[p][3] = fmaf(zr[p].y, er[1].w, acc[p][3]);
                    acc[p][3] = fmaf(zr[p].z, er[2].w, acc[p][3]);
                    acc[p][3] = fmaf(zr[p].w, er[3].w, acc[p][3]);
                }
            }
        }
        #pragma unroll
        for (int q = 0; q < 4; ++q) {
            const int kg = kc * KC + tx * 4 + q;
            const float en = ee_s[tx * 4 + q];
            #pragma unroll
            for (int p = 0; p < 4; ++p) {
                const float t = zz_s[ty * 4 + p] + en;
                const float d = t - 2.0f * acc[p][q];
                if (d < minv[p]) { minv[p] = d; mini[p] = kg; }
            }
        }
    }
    #pragma unroll
    for (int p = 0; p < 4; ++p) {
        red_v[ty * 4 + p][tx] = minv[p];
        red_i[ty * 4 + p][tx] = mini[p];
    }
    __syncthreads();
    if (tid < MP) {
        float bvv = red_v[tid][0]; int bii = red_i[tid][0];
        for (int q = 1; q < 32; ++q) {
            const float vq = red_v[tid][q]; const int iq = red_i[tid][q];
            if (vq < bvv || (vq == bvv && iq < bii)) { bvv = vq; bii = iq; }
        }
        idx_s[tid] = bii;
        out[NQ + m0 + tid] = (float)bii;
    }
    __syncthreads();
    float lsum = 0.0f;
    const size_t ebase = (size_t)idx_s[tx] * DIM;
    for (int it = 0; it < DIM / 8; ++it) {
        const int c = it * 8 + ty;
        const float e = emb[ebase + c];
        out[((size_t)(bimg * DIM + c)) * HW + hw0 + tx] = e;
        const float diff = e - zs[tx][c];
        lsum += diff * diff;
    }
    #pragma unroll
    for (int off = 32; off >= 1; off >>= 1) lsum += __shfl_down(lsum, off, 64);
    if ((tid & 63) == 0) wred[tid >> 6] = lsum;
    __syncthreads();
    if (tid == 0) part[blockIdx.x] = wred[0] + wred[1] + wred[2] + wred[3];
}

// ---------------------------------------------------------------------------
extern "C" void kernel_launch(void* const* d_in, const int* in_sizes, int n_in,
                              void* d_out, int out_size, void* d_ws, size_t ws_size,
                              hipStream_t stream) {
    const float* z   = (const float*)d_in[0];
    const float* emb = (const float*)d_in[1];
    float* out = (float*)d_out;
    char*  ws  = (char*)d_ws;

    float* zz   = (float*)(ws + 0);            // 256K
    float* ee   = (float*)(ws + 262144);       // 16K
    float* part = (float*)(ws + 278528);       // 8K
    int*   cnt  = (int*)  (ws + 286720);       // 4K
    int*   rlst = (int*)  (ws + 290816);       // 256K
    int*   idxf = (int*)  (ws + 552960);       // 256K
    float* t8v  = (float*)(ws + 1048576);      // 2M
    int*   t8i  = (int*)  (ws + 3145728);      // 2M
    ushort* eh  = (ushort*)(ws + 5242880);     // 2M (hi only)
    ushort* zh  = (ushort*)(ws + 7340032);     // 32M (hi only) -> ends 40894464
    float* m3f  = (float*)(ws + 40894464);     // 256K
    const size_t REQ = 74448896;               // ~71 MB (granted in R4-R18)

    ee_np_kernel<<<KCODES / 256, 256, 0, stream>>>(emb, ee);

    if (ws_size >= REQ) {
        hipMemsetAsync(cnt, 0, 4, stream);
        cvt_emb_kernel<<<KCODES / 4, 256, 0, stream>>>(emb, eh);
        cvt_z_kernel<<<1024, 256, 0, stream>>>(z, zh, zz);   // fused zz
        gemm_kernel<<<NPIX / 64, 256, 0, stream>>>(eh, zh, ee, zz, t8v, t8i, m3f);
        resolve_kernel<<<NPIX / 256, 256, 0, stream>>>(z, emb, zz, ee, t8v, t8i, m3f, idxf, cnt, rlst);
        rescan_kernel<<<2048, 256, 0, stream>>>(z, emb, zz, ee, cnt, rlst, idxf);
        gather_kernel<<<NPIX / 32, 256, 0, stream>>>(z, emb, idxf, out, part);
        loss_kernel<<<1, 256, 0, stream>>>(part, NPIX / 32, out);
    } else {
        zz_np_kernel<<<NPIX / 256, 256, 0, stream>>>(z, zz);
        safe_dist_kernel<<<NPIX / MP, 256, 0, stream>>>(z, emb, ee, zz, out, part);
        loss_kernel<<<1, 256, 0, stream>>>(part, NPIX / MP, out);
    }
}

// Round 20
// 492.517 us; speedup vs baseline: 1.5291x; 1.0564x over previous
//
#include <hip/hip_runtime.h>
#include <math.h>

#define KCODES 4096
#define DIM    256
#define HW     4096
#define NPIX   65536
#define NQ     16777216   // 16*256*64*64
#define EPSW   3.0e-4f    // hh-only scan: eps_max ~1.25e-4 rigorous; EPSW >= 2*eps

typedef _Float16 f16x8 __attribute__((ext_vector_type(8)));
typedef float    f32x4 __attribute__((ext_vector_type(4)));

// XOR swizzle on tile-local byte offset (within 8KB chunk of 128 rows x 64B).
#define SWZ(x) ((x) ^ ((((x) >> 6) & 7) << 4))

static __device__ __forceinline__ void gld16(const void* g, void* l) {
    __builtin_amdgcn_global_load_lds(
        (const __attribute__((address_space(1))) void*)g,
        (__attribute__((address_space(3))) void*)l, 16, 0, 0);
}

// top4 insert, strict < (ascending-k feed => lowest k kept on ties; a tie-drop
// at V[3] is covered by the m3<=lim rescan flag)
#define INS4(V, I, dd, kk) do { \
  if ((dd) < V[3]) { \
    if ((dd) < V[1]) { \
      V[3]=V[2]; I[3]=I[2]; V[2]=V[1]; I[2]=I[1]; \
      if ((dd) < V[0]) { V[1]=V[0]; I[1]=I[0]; V[0]=(dd); I[0]=(kk); } \
      else             { V[1]=(dd); I[1]=(kk); } \
    } else { \
      if ((dd) < V[2]) { V[3]=V[2]; I[3]=I[2]; V[2]=(dd); I[2]=(kk); } \
      else             { V[3]=(dd); I[3]=(kk); } \
    } } } while(0)

// top8 insert (merge-time only), strict <; tie-drops at V[7] covered by flag
#define INS8(V, I, dd, kk) do { \
  if ((dd) < V[7]) { \
    if ((dd) < V[3]) { \
      V[7]=V[6];I[7]=I[6];V[6]=V[5];I[6]=I[5];V[5]=V[4];I[5]=I[4];V[4]=V[3];I[4]=I[3]; \
      if ((dd) < V[1]) { \
        V[3]=V[2];I[3]=I[2];V[2]=V[1];I[2]=I[1]; \
        if ((dd) < V[0]) { V[1]=V[0];I[1]=I[0];V[0]=(dd);I[0]=(kk); } \
        else             { V[1]=(dd);I[1]=(kk); } \
      } else { \
        if ((dd) < V[2]) { V[3]=V[2];I[3]=I[2];V[2]=(dd);I[2]=(kk); } \
        else             { V[3]=(dd);I[3]=(kk); } \
      } \
    } else { \
      if ((dd) < V[5]) { \
        V[7]=V[6];I[7]=I[6];V[6]=V[5];I[6]=I[5]; \
        if ((dd) < V[4]) { V[5]=V[4];I[5]=I[4];V[4]=(dd);I[4]=(kk); } \
        else             { V[5]=(dd);I[5]=(kk); } \
      } else { \
        if ((dd) < V[6]) { V[7]=V[6];I[7]=I[6];V[6]=(dd);I[6]=(kk); } \
        else             { V[7]=(dd);I[7]=(kk); } \
      } \
    } } } while(0)

// ---------------------------------------------------------------------------
// np-exact helpers (bit-replicate numpy f32 semantics — proven in R3)
// ---------------------------------------------------------------------------
__global__ __launch_bounds__(256) void ee_np_kernel(const float* __restrict__ emb,
                                                    float* __restrict__ ee) {
#pragma clang fp contract(off)
    const int k = blockIdx.x * 256 + threadIdx.x;
    const float* a = emb + (size_t)k * DIM;
    float res[2];
    #pragma unroll
    for (int h = 0; h < 2; ++h) {
        const float* b = a + h * 128;
        float r[8];
        #pragma unroll
        for (int j = 0; j < 8; ++j) { const float x = b[j]; r[j] = x * x; }
        for (int i = 8; i < 128; i += 8) {
            #pragma unroll
            for (int j = 0; j < 8; ++j) { const float x = b[i + j]; r[j] += x * x; }
        }
        res[h] = ((r[0] + r[1]) + (r[2] + r[3])) + ((r[4] + r[5]) + (r[6] + r[7]));
    }
    ee[k] = res[0] + res[1];
}

// standalone zz (SAFE path only; fast path computes zz inside cvt_z)
__global__ __launch_bounds__(256) void zz_np_kernel(const float* __restrict__ z,
                                                    float* __restrict__ zz) {
#pragma clang fp contract(off)
    const int n  = blockIdx.x * 256 + threadIdx.x;
    const int b  = n >> 12;
    const int hw = n & (HW - 1);
    const float* base = z + (size_t)b * DIM * HW + hw;
    float res[2];
    #pragma unroll
    for (int h = 0; h < 2; ++h) {
        const float* p = base + (size_t)(h * 128) * HW;
        float r[8];
        #pragma unroll
        for (int j = 0; j < 8; ++j) { const float x = p[(size_t)j * HW]; r[j] = x * x; }
        for (int i = 8; i < 128; i += 8) {
            #pragma unroll
            for (int j = 0; j < 8; ++j) { const float x = p[(size_t)(i + j) * HW]; r[j] += x * x; }
        }
        res[h] = ((r[0] + r[1]) + (r[2] + r[3])) + ((r[4] + r[5]) + (r[6] + r[7]));
    }
    zz[n] = res[0] + res[1];
}

__device__ float np_dist(const float* __restrict__ z, const float* __restrict__ emb,
                         const float* __restrict__ zz, const float* __restrict__ ee,
                         int n, int k) {
    const int b = n >> 12, hw = n & (HW - 1);
    const float* zp = z + (size_t)b * DIM * HW + hw;
    const float* ep = emb + (size_t)k * DIM;
    float m = 0.0f;
    for (int i = 0; i < DIM; ++i) m = fmaf(zp[(size_t)i * HW], ep[i], m);
    const float t = zz[n] + ee[k];
    return t - 2.0f * m;
}

// ---------------------------------------------------------------------------
// FAST path kernels
// ---------------------------------------------------------------------------
// emb -> tiled fp16 HI only, scaled by 4096 (exact pow2), PRE-SWIZZLED.
__global__ __launch_bounds__(256) void cvt_emb_kernel(const float* __restrict__ emb,
                                                      ushort* __restrict__ eh) {
    const int t = threadIdx.x;
    const int k = blockIdx.x * 4 + (t >> 6);
    const int seg = t & 63;                       // 4-elem segment
    const float4 v = *reinterpret_cast<const float4*>(emb + (size_t)k * DIM + seg * 4);
    union H4 { _Float16 h[4]; short4 s; } uh;
    const float vv[4] = {v.x, v.y, v.z, v.w};
    #pragma unroll
    for (int j = 0; j < 4; ++j) uh.h[j] = (_Float16)(vv[j] * 4096.0f);
    const int s = seg >> 3;
    const int y  = (k & 127) * 64 + (seg & 7) * 8;        // logical byte in 8KB chunk
    const int ys = y ^ ((k & 7) << 4);                    // pre-swizzled
    const size_t addr = (size_t)(k >> 7) * 32768 + s * 4096 + (ys >> 1);
    *reinterpret_cast<short4*>(eh + addr) = uh.s;
}

// z (NCHW) -> transposed tiled fp16 HI [pixel][dim], PRE-SWIZZLED.
// FUSED zz (numpy pairwise-8, bit-exact). float4 global loads (1KB/wave-inst).
// Block = 64 pixels x ALL 256 channels (grid 1024).
__global__ __launch_bounds__(256) void cvt_z_kernel(const float* __restrict__ z,
                                                    ushort* __restrict__ zh,
                                                    float* __restrict__ zz) {
#pragma clang fp contract(off)
    __shared__ float ls[256][68];   // [channel][pixel], pad 68 keeps 16B align
    const int t = threadIdx.x;
    const int bid = blockIdx.x;
    const int b = bid >> 6, hh = bid & 63;
    const int c4 = t & 15, r0 = t >> 4;   // col4 0..15, row-base 0..15
    #pragma unroll
    for (int i = 0; i < 16; ++i) {
        const int c = i * 16 + r0;
        const float4 v = *reinterpret_cast<const float4*>(
            z + ((size_t)(b * DIM + c)) * HW + hh * 64 + c4 * 4);
        *reinterpret_cast<float4*>(&ls[c][c4 * 4]) = v;
    }
    __syncthreads();

    // zz for the 64 pixels (numpy pairwise order, bit-exact)
    if (t < 64) {
        float res[2];
        #pragma unroll
        for (int h = 0; h < 2; ++h) {
            const int base = h * 128;
            float r[8];
            #pragma unroll
            for (int j = 0; j < 8; ++j) { const float x = ls[base + j][t]; r[j] = x * x; }
            for (int i = 8; i < 128; i += 8) {
                #pragma unroll
                for (int j = 0; j < 8; ++j) { const float x = ls[base + i + j][t]; r[j] += x * x; }
            }
            res[h] = ((r[0] + r[1]) + (r[2] + r[3])) + ((r[4] + r[5]) + (r[6] + r[7]));
        }
        zz[b * HW + hh * 64 + t] = res[0] + res[1];
    }

    // fp16 conversion + pre-swizzled tiled stores (each thread: 64 channels)
    const int pxl = t >> 2, cseg = t & 3;
    const int px = b * HW + hh * 64 + pxl;
    const size_t chunkb = (size_t)(px >> 7) * 32768;
    const int msk = (px & 7) << 4;
    #pragma unroll
    for (int g = 0; g < 4; ++g) {
        const int cb = cseg * 64 + g * 16;     // channel base (16 channels)
        union H8 { _Float16 h[8]; int4 v; } ha, hb;
        #pragma unroll
        for (int j = 0; j < 16; ++j) {
            const float val = ls[cb + j][pxl];
            if (j < 8) ha.h[j] = (_Float16)val;
            else       hb.h[j - 8] = (_Float16)val;
        }
        const int sg = cb >> 5;                                // dim-subchunk 0..7
        const int y1 = (px & 127) * 64 + ((cb >> 4) & 1) * 32; // byte in 8KB chunk
        *reinterpret_cast<int4*>(zh + chunkb + sg * 4096 + ((y1 ^ msk) >> 1))        = ha.v;
        *reinterpret_cast<int4*>(zh + chunkb + sg * 4096 + (((y1 + 16) ^ msk) >> 1)) = hb.v;
    }
}

// MFMA distance pass (hh-only): block = 64 pixels x 4096 codes. (R16-proven
// main loop.) z fragments REGISTER-RESIDENT; code chunks (16KB) double-
// buffered via gld16. FUSED RESOLVE in the merge tail: certificate +
// np-exact candidate re-evaluation + rescan flagging, all in-register.
__global__ __launch_bounds__(256, 3) void gemm_kernel(const ushort* __restrict__ eh,
                                                      const ushort* __restrict__ zh,
                                                      const float* __restrict__ ee,
                                                      const float* __restrict__ zz,
                                                      const float* __restrict__ z,
                                                      const float* __restrict__ emb,
                                                      int* __restrict__ idxf,
                                                      int* __restrict__ cnt,
                                                      int* __restrict__ rlist) {
    __shared__ __align__(16) char et[2][16384];  // code dbuf: 2 x (2 s-chunks)

    const int t = threadIdx.x;
    const int lane = t & 63, w = t >> 6, wr = w >> 1, wc = w & 1;
    const int l15 = lane & 15, l4 = lane >> 4;
    const int bid = blockIdx.x;
    const int px0 = bid * 64;
    const int lo = t * 16;            // per-lane linear byte offset within 4KB round
    const int wb = w * 1024;          // wave-uniform LDS base
    const char* ehB = (const char*)eh;

    // ---- load z fragments into registers (once) ----
    f16x8 zr[2][8];
    {
        const size_t chunk = (size_t)(bid >> 1) * 32768;   // halfs
        #pragma unroll
        for (int ni = 0; ni < 2; ++ni) {
            const int lr = (bid & 1) * 64 + wc * 32 + ni * 16 + l15;  // row in 128-chunk
            const int ro = SWZ(lr * 64 + l4 * 16) >> 1;               // halfs
            #pragma unroll
            for (int s = 0; s < 8; ++s)
                zr[ni][s] = *reinterpret_cast<const f16x8*>(zh + chunk + s * 4096 + ro);
        }
    }
    float zzr[2];
    #pragma unroll
    for (int ni = 0; ni < 2; ++ni) zzr[ni] = zz[px0 + wc * 32 + ni * 16 + l15];

    // per-lane code-fragment byte offsets within an 8KB dim-subchunk
    int aoff[4];
    #pragma unroll
    for (int mi = 0; mi < 4; ++mi)
        aoff[mi] = SWZ((wr * 64 + mi * 16 + l15) * 64 + l4 * 16);

    // ---- stage first 16KB code step ----
    #pragma unroll
    for (int r = 0; r < 4; ++r)
        gld16(ehB + r * 4096 + lo, et[0] + r * 4096 + wb);
    __syncthreads();

    float Tv[2][4]; int Ti[2][4];
    #pragma unroll
    for (int ni = 0; ni < 2; ++ni)
        #pragma unroll
        for (int j = 0; j < 4; ++j) { Tv[ni][j] = 3.0e38f; Ti[ni][j] = 0; }

    for (int p = 0; p < 32; ++p) {
        float eer[4][4];
        #pragma unroll
        for (int mi = 0; mi < 4; ++mi)
            #pragma unroll
            for (int r = 0; r < 4; ++r)
                eer[mi][r] = ee[p * 128 + wr * 64 + mi * 16 + l4 * 4 + r];

        f32x4 acc[4][2];
        #pragma unroll
        for (int mi = 0; mi < 4; ++mi)
            #pragma unroll
            for (int ni = 0; ni < 2; ++ni)
                acc[mi][ni] = (f32x4){0.0f, 0.0f, 0.0f, 0.0f};

        #pragma unroll
        for (int st = 0; st < 4; ++st) {
            const int cur = st & 1;            // compile-time buffer parity
            // prefetch next 16KB step into the other buffer
            if (st < 3 || p < 31) {
                const size_t nb = ((size_t)(p * 4 + st) + 1) * 16384;
                #pragma unroll
                for (int r = 0; r < 4; ++r)
                    gld16(ehB + nb + r * 4096 + lo, et[cur ^ 1] + r * 4096 + wb);
            }
            #pragma unroll
            for (int sp = 0; sp < 2; ++sp) {
                const int sg = st * 2 + sp;    // global s 0..7
                f16x8 aH[4];
                #pragma unroll
                for (int mi = 0; mi < 4; ++mi)
                    aH[mi] = *reinterpret_cast<const f16x8*>(et[cur] + sp * 8192 + aoff[mi]);
                #pragma unroll
                for (int mi = 0; mi < 4; ++mi)
                    #pragma unroll
                    for (int ni = 0; ni < 2; ++ni)
                        acc[mi][ni] = __builtin_amdgcn_mfma_f32_16x16x32_f16(aH[mi], zr[ni][sg], acc[mi][ni], 0, 0, 0);
            }
            __syncthreads();   // et[cur] reads done; et[cur^1] loads landed
        }
        // epilogue: d = fl((zz+ee) - acc*2^-11), per-thread top4 (ascending k)
        #pragma unroll
        for (int ni = 0; ni < 2; ++ni) {
            const float zzc = zzr[ni];
            #pragma unroll
            for (int mi = 0; mi < 4; ++mi) {
                #pragma unroll
                for (int r = 0; r < 4; ++r) {
                    const float tt = zzc + eer[mi][r];
                    const float d = fmaf(acc[mi][ni][r], -4.8828125e-4f, tt);
                    const int k = p * 128 + wr * 64 + mi * 16 + l4 * 4 + r;
                    INS4(Tv[ni], Ti[ni], d, k);
                }
            }
        }
    }

    // merge arrays alias the code buffers (dead after the loop)
    float (*mv)[64][8]  = reinterpret_cast<float (*)[64][8]>(&et[0][0]);
    int   (*mi_)[64][8] = reinterpret_cast<int (*)[64][8]>(&et[0][8192]);
    float (*m3s)[64]    = reinterpret_cast<float (*)[64]>(&et[1][0]);

    // per-ni: expand top4 -> top8, merge across l4 lanes (xor16/xor32), track m3
    #pragma unroll
    for (int ni = 0; ni < 2; ++ni) {
        float fv[8]; int fi[8];
        #pragma unroll
        for (int j = 0; j < 4; ++j) { fv[j] = Tv[ni][j]; fi[j] = Ti[ni][j]; }
        #pragma unroll
        for (int j = 4; j < 8; ++j) { fv[j] = 3.0e38f; fi[j] = 0; }
        float m3 = Tv[ni][3];          // pre-merge thread-local 4th best
        #pragma unroll
        for (int m = 16; m <= 32; m <<= 1) {
            float ov[8]; int oi[8];
            #pragma unroll
            for (int j = 0; j < 8; ++j) {
                ov[j] = __shfl_xor(fv[j], m, 64);
                oi[j] = __shfl_xor(fi[j], m, 64);
            }
            const float om = __shfl_xor(m3, m, 64);
            #pragma unroll
            for (int j = 0; j < 8; ++j) INS8(fv, fi, ov[j], oi[j]);
            m3 = fminf(m3, om);
        }
        if (lane < 16) {
            const int c = wc * 32 + ni * 16 + lane;
            #pragma unroll
            for (int j = 0; j < 8; ++j) { mv[wr][c][j] = fv[j]; mi_[wr][c][j] = fi[j]; }
            m3s[wr][c] = m3;
        }
    }
    __syncthreads();
    if (t < 64) {
        float fv[8]; int fi[8];
        #pragma unroll
        for (int j = 0; j < 8; ++j) { fv[j] = mv[0][t][j]; fi[j] = mi_[0][t][j]; }
        #pragma unroll
        for (int j = 0; j < 8; ++j) INS8(fv, fi, mv[1][t][j], mi_[1][t][j]);
        const float m3 = fminf(m3s[0][t], m3s[1][t]);
        const int px = px0 + t;

        // ---- FUSED RESOLVE (np-exact; same logic as the old resolve kernel) ----
        const float lim = fv[0] + EPSW;
        int res = fi[0];
        if (fv[7] <= lim || m3 <= lim) {     // union certificate failed -> rescan
            const int pos = atomicAdd(cnt, 1);
            rlist[pos] = px;
        } else if (fv[1] <= lim) {           // near-ties: np-exact re-evaluation
            int ck[8]; int nc = 0;
            for (int j = 0; j < 8; ++j) if (fv[j] <= lim) ck[nc++] = fi[j];
            for (int a = 0; a < nc - 1; ++a)      // sort by k ascending
                for (int b2 = a + 1; b2 < nc; ++b2)
                    if (ck[b2] < ck[a]) { int tmp = ck[a]; ck[a] = ck[b2]; ck[b2] = tmp; }
            float best = 0.0f; int bk = -1;
            for (int a = 0; a < nc; ++a) {
                const float d = np_dist(z, emb, zz, ee, px, ck[a]);
                if (bk < 0 || d < best) { best = d; bk = ck[a]; }
            }
            res = bk;
        }
        idxf[px] = res;
    }
}

// full np-exact rescan for flagged pixels (wave-parallel reduce, wide grid)
__global__ __launch_bounds__(256) void rescan_kernel(const float* __restrict__ z,
                                                     const float* __restrict__ emb,
                                                     const float* __restrict__ zz,
                                                     const float* __restrict__ ee,
                                                     const int* __restrict__ cnt,
                                                     const int* __restrict__ rlist,
                                                     int* __restrict__ idxf) {
#pragma clang fp contract(off)
    __shared__ float ls[DIM];
    __shared__ float wv[4];
    __shared__ int   wk[4];
    const int t = threadIdx.x;
    const int lane = t & 63, w = t >> 6;
    const int count = *cnt;
    for (int e = blockIdx.x; e < count; e += gridDim.x) {
        const int n = rlist[e];
        const int b = n >> 12, hw = n & (HW - 1);
        __syncthreads();   // protect ls/wv/wk from previous iteration's readers
        ls[t] = z[((size_t)(b * DIM + t)) * HW + hw];
        __syncthreads();
        const float zzn = zz[n];
        float bestd = 3.0e38f; int besti = 0x7fffffff;
        for (int j = 0; j < 16; ++j) {
            const int k = t + j * 256;
            const float* ep = emb + (size_t)k * DIM;
            float m = 0.0f;
            for (int i = 0; i < DIM; ++i) m = fmaf(ls[i], ep[i], m);
            const float d = (zzn + ee[k]) - 2.0f * m;
            if (d < bestd || (d == bestd && k < besti)) { bestd = d; besti = k; }
        }
        // wave-level lexicographic (d, k) min
        #pragma unroll
        for (int off = 32; off >= 1; off >>= 1) {
            const float od = __shfl_down(bestd, off, 64);
            const int   ok = __shfl_down(besti, off, 64);
            if (od < bestd || (od == bestd && ok < besti)) { bestd = od; besti = ok; }
        }
        if (lane == 0) { wv[w] = bestd; wk[w] = besti; }
        __syncthreads();
        if (t == 0) {
            float bd = wv[0]; int bi = wk[0];
            #pragma unroll
            for (int q = 1; q < 4; ++q)
                if (wv[q] < bd || (wv[q] == bd && wk[q] < bi)) { bd = wv[q]; bi = wk[q]; }
            idxf[n] = bi;
        }
    }
}

// gather z_q + idx output + loss partials; emb rows STAGED in LDS (coalesced)
__global__ __launch_bounds__(256) void gather_kernel(const float* __restrict__ z,
                                                     const float* __restrict__ emb,
                                                     const int* __restrict__ idxf,
                                                     float* __restrict__ out,
                                                     float* __restrict__ part) {
    __shared__ int   idx_s[32];
    __shared__ float es[32][257];
    __shared__ float wred[4];
    const int tid = threadIdx.x;
    const int tx = tid & 31, ty = tid >> 5;
    const int m0 = blockIdx.x * 32;
    const int bimg = m0 >> 12, hw0 = m0 & (HW - 1);
    if (tid < 32) {
        const int ii = idxf[m0 + tid];
        idx_s[tid] = ii;
        out[NQ + m0 + tid] = (float)ii;
    }
    __syncthreads();
    // stage the 32 gathered emb rows (each iter: one coalesced 1KB read)
    for (int r = 0; r < 32; ++r)
        es[r][tid] = emb[(size_t)idx_s[r] * DIM + tid];
    __syncthreads();
    float lsum = 0.0f;
    for (int it = 0; it < DIM / 8; ++it) {
        const int c = it * 8 + ty;
        const float e = es[tx][c];
        const size_t zoff = ((size_t)(bimg * DIM + c)) * HW + hw0 + tx;
        out[zoff] = e;
        const float diff = e - z[zoff];
        lsum += diff * diff;
    }
    #pragma unroll
    for (int off = 32; off >= 1; off >>= 1) lsum += __shfl_down(lsum, off, 64);
    if ((tid & 63) == 0) wred[tid >> 6] = lsum;
    __syncthreads();
    if (tid == 0) part[blockIdx.x] = wred[0] + wred[1] + wred[2] + wred[3];
}

__global__ __launch_bounds__(256) void loss_kernel(const float* __restrict__ part,
                                                   int nblk, float* __restrict__ out) {
    __shared__ float wred[4];
    const int tid = threadIdx.x;
    float s = 0.0f;
    for (int i = tid; i < nblk; i += 256) s += part[i];
    #pragma unroll
    for (int off = 32; off >= 1; off >>= 1) s += __shfl_down(s, off, 64);
    if ((tid & 63) == 0) wred[tid >> 6] = s;
    __syncthreads();
    if (tid == 0) {
        const float total = wred[0] + wred[1] + wred[2] + wred[3];
        out[NQ + NPIX] = 1.25f * total / 16777216.0f;
    }
}

// ---------------------------------------------------------------------------
// SAFE path: R3's proven fused VALU kernel (used when ws too small)
// ---------------------------------------------------------------------------
#define MP 32
#define KC 128
#define DC 32
__global__ __launch_bounds__(256) void safe_dist_kernel(const float* __restrict__ z,
                                                        const float* __restrict__ emb,
                                                        const float* __restrict__ ee,
                                                        const float* __restrict__ zz,
                                                        float* __restrict__ out,
                                                        float* __restrict__ part) {
    __shared__ float zs[MP][DIM + 4];
    __shared__ float est[DC][KC + 4];
    __shared__ float ee_s[KC];
    __shared__ float zz_s[MP];
    __shared__ float red_v[MP][33];
    __shared__ int   red_i[MP][33];
    __shared__ int   idx_s[MP];
    __shared__ float wred[4];

    const int tid = threadIdx.x;
    const int tx = tid & 31, ty = tid >> 5;
    const int m0 = blockIdx.x * MP;
    const int bimg = m0 >> 12, hw0 = m0 & (HW - 1);

    for (int c = ty; c < DIM; c += 8)
        zs[tx][c] = z[((size_t)(bimg * DIM + c)) * HW + hw0 + tx];
    if (tid < MP) zz_s[tid] = zz[m0 + tid];

    float minv[4]; int mini[4];
    #pragma unroll
    for (int p = 0; p < 4; ++p) { minv[p] = 3.0e38f; mini[p] = 0; }
    const int rl = tid >> 3, cl = tid & 7;

    for (int kc = 0; kc < KCODES / KC; ++kc) {
        float acc[4][4];
        #pragma unroll
        for (int p = 0; p < 4; ++p)
            #pragma unroll
            for (int q = 0; q < 4; ++q) acc[p][q] = 0.0f;
        for (int dc = 0; dc < DIM / DC; ++dc) {
            __syncthreads();
            if (dc == 0 && tid < KC) ee_s[tid] = ee[kc * KC + tid];
            #pragma unroll
            for (int it = 0; it < 4; ++it) {
                const int kl = it * 32 + rl;
                const float4 v = *reinterpret_cast<const float4*>(
                    emb + (size_t)(kc * KC + kl) * DIM + dc * DC + cl * 4);
                est[cl * 4 + 0][kl] = v.x;
                est[cl * 4 + 1][kl] = v.y;
                est[cl * 4 + 2][kl] = v.z;
                est[cl * 4 + 3][kl] = v.w;
            }
            __syncthreads();
            #pragma unroll
            for (int g = 0; g < DC / 4; ++g) {
                float4 zr[4];
                #pragma unroll
                for (int p = 0; p < 4; ++p)
                    zr[p] = *reinterpret_cast<const float4*>(&zs[ty * 4 + p][dc * DC + g * 4]);
                float4 er[4];
                #pragma unroll
                for (int j = 0; j < 4; ++j)
                    er[j] = *reinterpret_cast<const float4*>(&est[g * 4 + j][tx * 4]);
                #pragma unroll
                for (int p = 0; p < 4; ++p) {
                    acc[p][0] = fmaf(zr[p].x, er[0].x, acc[p][0]);
                    acc[p][0] = fmaf(zr[p].y, er[1].x, acc[p][0]);
                    acc[p][0] = fmaf(zr[p].z, er[2].x, acc[p][0]);
                    acc[p][0] = fmaf(zr[p].w, er[3].x, acc[p][0]);
                    acc[p][1] = fmaf(zr[p].x, er[0].y, acc[p][1]);
                    acc[p][1] = fmaf(zr[p].y, er[1].y, acc[p][1]);
                    acc[p][1] = fmaf(zr[p].z, er[2].y, acc[p][1]);
                    acc[p][1] = fmaf(zr[p].w, er[3].y, acc[p][1]);
                    acc[p][2] = fmaf(zr[p].x, er[0].z, acc[p][2]);
                    acc[p][2] = fmaf(zr[p].y, er[1].z, acc[p][2]);
                    acc[p][2] = fmaf(zr[p].z, er[2].z, acc[p][2]);
                    acc[p][2] = fmaf(zr[p].w, er[3].z, acc[p][2]);
                    acc[p][3] = fmaf(zr[p].x, er[0].w, acc[p][3]);
                    acc[p][3] = fmaf(zr[p].y, er[1].w, acc[p][3]);
                    acc[p][3] = fmaf(zr[p].z, er[2].w, acc[p][3]);
                    acc[p][3] = fmaf(zr[p].w, er[3].w, acc[p][3]);
                }
            }
        }
        #pragma unroll
        for (int q = 0; q < 4; ++q) {
            const int kg = kc * KC + tx * 4 + q;
            const float en = ee_s[tx * 4 + q];
            #pragma unroll
            for (int p = 0; p < 4; ++p) {
                const float t = zz_s[ty * 4 + p] + en;
                const float d = t - 2.0f * acc[p][q];
                if (d < minv[p]) { minv[p] = d; mini[p] = kg; }
            }
        }
    }
    #pragma unroll
    for (int p = 0; p < 4; ++p) {
        red_v[ty * 4 + p][tx] = minv[p];
        red_i[ty * 4 + p][tx] = mini[p];
    }
    __syncthreads();
    if (tid < MP) {
        float bvv = red_v[tid][0]; int bii = red_i[tid][0];
        for (int q = 1; q < 32; ++q) {
            const float vq = red_v[tid][q]; const int iq = red_i[tid][q];
            if (vq < bvv || (vq == bvv && iq < bii)) { bvv = vq; bii = iq; }
        }
        idx_s[tid] = bii;
        out[NQ + m0 + tid] = (float)bii;
    }
    __syncthreads();
    float lsum = 0.0f;
    const size_t ebase = (size_t)idx_s[tx] * DIM;
    for (int it = 0; it < DIM / 8; ++it) {
        const int c = it * 8 + ty;
        const float e = emb[ebase + c];
        out[((size_t)(bimg * DIM + c)) * HW + hw0 + tx] = e;
        const float diff = e - zs[tx][c];
        lsum += diff * diff;
    }
    #pragma unroll
    for (int off = 32; off >= 1; off >>= 1) lsum += __shfl_down(lsum, off, 64);
    if ((tid & 63) == 0) wred[tid >> 6] = lsum;
    __syncthreads();
    if (tid == 0) part[blockIdx.x] = wred[0] + wred[1] + wred[2] + wred[3];
}

// ---------------------------------------------------------------------------
extern "C" void kernel_launch(void* const* d_in, const int* in_sizes, int n_in,
                              void* d_out, int out_size, void* d_ws, size_t ws_size,
                              hipStream_t stream) {
    const float* z   = (const float*)d_in[0];
    const float* emb = (const float*)d_in[1];
    float* out = (float*)d_out;
    char*  ws  = (char*)d_ws;

    float* zz   = (float*)(ws + 0);            // 256K
    float* ee   = (float*)(ws + 262144);       // 16K
    float* part = (float*)(ws + 278528);       // 8K
    int*   cnt  = (int*)  (ws + 286720);       // 4K
    int*   rlst = (int*)  (ws + 290816);       // 256K
    int*   idxf = (int*)  (ws + 552960);       // 256K
    ushort* eh  = (ushort*)(ws + 5242880);     // 2M (hi only)
    ushort* zh  = (ushort*)(ws + 7340032);     // 32M (hi only) -> ends 40894464
    const size_t REQ = 74448896;               // ~71 MB (granted in R4-R19)

    ee_np_kernel<<<KCODES / 256, 256, 0, stream>>>(emb, ee);

    if (ws_size >= REQ) {
        hipMemsetAsync(cnt, 0, 4, stream);
        cvt_emb_kernel<<<KCODES / 4, 256, 0, stream>>>(emb, eh);
        cvt_z_kernel<<<1024, 256, 0, stream>>>(z, zh, zz);   // fused zz
        gemm_kernel<<<NPIX / 64, 256, 0, stream>>>(eh, zh, ee, zz, z, emb, idxf, cnt, rlst);
        rescan_kernel<<<2048, 256, 0, stream>>>(z, emb, zz, ee, cnt, rlst, idxf);
        gather_kernel<<<NPIX / 32, 256, 0, stream>>>(z, emb, idxf, out, part);
        loss_kernel<<<1, 256, 0, stream>>>(part, NPIX / 32, out);
    } else {
        zz_np_kernel<<<NPIX / 256, 256, 0, stream>>>(z, zz);
        safe_dist_kernel<<<NPIX / MP, 256, 0, stream>>>(z, emb, ee, zz, out, part);
        loss_kernel<<<1, 256, 0, stream>>>(part, NPIX / MP, out);
    }
}